// Round 3
// baseline (169.329 us; speedup 1.0000x reference)
//
#include <hip/hip_runtime.h>

#define BS 1024
#define D 128
#define NC 100000
#define NCP 100096           /* padded to 782*128 */
#define NTILES 782
#define S_SCALE 30.0f
#define MARGIN 0.35f
#define S2LOG2E 43.2808512f  /* 30 * log2(e): exp(30c-30) == exp2(fma(c,S2,-S2)) */

typedef __attribute__((ext_vector_type(8))) short bf16x8;
typedef __attribute__((ext_vector_type(4))) float f32x4;

__device__ __forceinline__ unsigned short f2bf(float f) {
    union { float f; unsigned u; } x; x.f = f;
    unsigned u = x.u;
    u += 0x7FFFu + ((u >> 16) & 1u);   // round-to-nearest-even
    return (unsigned short)(u >> 16);
}

// Fragment-sequential bf16 layout (operand-role-agnostic):
//   u32 index for (row r, lane l holding k=2l,2l+1):
//     (r>>4)*1024 + (l>>2)*64 + (r&15)*4 + (l&3)
// A 16-row x 32-k fragment is one CONTIGUOUS 1KB wave-load:
//     byte = (row_block)*4096 + ks*1024 + lane*16

// 4 rows per block (4 waves): l2-normalize input rows, emit f32 + frag bf16,
// count labels, and pos[row] = S * dot(fn, l2norm(weight[label])) in f32.
__global__ void prep_fn(const float* __restrict__ inp, const int* __restrict__ label,
                        const float* __restrict__ wt,
                        float* __restrict__ fn_f32, unsigned short* __restrict__ fn_fr,
                        float* __restrict__ counts, float* __restrict__ pos) {
    int row = blockIdx.x * 4 + (threadIdx.x >> 6);
    int lane = threadIdx.x & 63;
    float2 v = *(const float2*)(inp + row * D + lane * 2);
    float s = v.x * v.x + v.y * v.y;
    #pragma unroll
    for (int m = 1; m < 64; m <<= 1) s += __shfl_xor(s, m);
    float inv = 1.0f / fmaxf(sqrtf(s), 1e-12f);
    float a = v.x * inv, b = v.y * inv;
    *(float2*)(fn_f32 + row * D + lane * 2) = make_float2(a, b);
    unsigned pack = (unsigned)f2bf(a) | ((unsigned)f2bf(b) << 16);
    ((unsigned*)fn_fr)[(row >> 4) * 1024 + (lane >> 2) * 64 + ((row & 15) << 2) + (lane & 3)] = pack;

    int c = label[row];
    float2 wv = *(const float2*)(wt + c * D + lane * 2);
    float sw_ = wv.x * wv.x + wv.y * wv.y;
    float dt  = wv.x * a + wv.y * b;
    #pragma unroll
    for (int m = 1; m < 64; m <<= 1) { sw_ += __shfl_xor(sw_, m); dt += __shfl_xor(dt, m); }
    if (lane == 0) {
        float invw = 1.0f / fmaxf(sqrtf(sw_), 1e-12f);
        pos[row] = S_SCALE * dt * invw;
        atomicAdd(counts + c, 1.0f);
    }
}

// 4 waves/block, one weight row per wave: l2-normalize -> frag-layout bf16 global.
// Fused: write weight output (copy if class absent, 0 if present). Pad rows -> 0.
__global__ void prep_wn(const float* __restrict__ wt, const float* __restrict__ counts,
                        unsigned short* __restrict__ wn_fr, float* __restrict__ outw) {
    int wv = threadIdx.x >> 6, lane = threadIdx.x & 63;
    int row = blockIdx.x * 4 + wv;      // grid 25024 -> 100096 incl. pad
    unsigned* dst = (unsigned*)wn_fr + (row >> 4) * 1024 + (lane >> 2) * 64 +
                    ((row & 15) << 2) + (lane & 3);
    if (row < NC) {
        float2 v = *(const float2*)(wt + row * D + lane * 2);
        float s = v.x * v.x + v.y * v.y;
        #pragma unroll
        for (int m = 1; m < 64; m <<= 1) s += __shfl_xor(s, m);
        float inv = 1.0f / fmaxf(sqrtf(s), 1e-12f);
        *dst = (unsigned)f2bf(v.x * inv) | ((unsigned)f2bf(v.y * inv) << 16);
        float cnt = counts[row];
        float2 o = (cnt > 0.0f) ? make_float2(0.0f, 0.0f) : v;
        *(float2*)(outw + row * D + lane * 2) = o;
    } else {
        *dst = 0u;   // pad classes: zero vector -> logit 0 -> e^-30, negligible
    }
}

// Main fused GEMM + exp-accumulate. v4: operand-swapped (A = wn classes, B = fn batch).
// Each block owns ONE 128-class wn tile (read exactly once from HBM -> 25.6 MB total,
// was 400 MB of L3 re-reads) and streams all 1024 batch rows (fn = 256 KB, L2-resident
// on every XCD) through registers in 16 chunks of 64. The class axis (the reduction
// axis of logsumexp) lives in register/quad indices -> the exp-sum needs no per-tile
// cross-lane reduce; batch (kept axis) lives in lanes. No LDS staging, no barriers in
// the hot loop; per-block partials accumulate in 4 KB LDS; one atomic flush at end.
// Wave = 64 classes x 32 batch: af 64 + b 32 + acc 32 VGPRs -> 3 waves/SIMD.
__global__ __launch_bounds__(256, 3) void main_gemm(
    const unsigned short* __restrict__ fnfr, const unsigned short* __restrict__ wnfr,
    float* __restrict__ sumexp) {
    __shared__ float red[1024];
    int tid = threadIdx.x;
    int lane = tid & 63, w = tid >> 6;
    int l15 = lane & 15;
    int cls_half = w >> 1;   // classes +0 / +64 within the 128-class tile
    int bat_half = w & 1;    // batch   +0 / +32 within the 64-batch chunk

    #pragma unroll
    for (int i = 0; i < 4; i++) red[tid + i * 256] = 0.0f;

    // A = wn tile fragments: 16 contiguous 1KB wave-loads, resident all kernel.
    bf16x8 af[4][4];   // [ks][mt]
    {
        const char* gA = (const char*)wnfr + (size_t)blockIdx.x * 32768 +
                         cls_half * 16384 + lane * 16;
        #pragma unroll
        for (int mt = 0; mt < 4; mt++)
            #pragma unroll
            for (int ks = 0; ks < 4; ks++)
                af[ks][mt] = *(const bf16x8*)(gA + mt * 4096 + ks * 1024);
    }

    __syncthreads();   // red[] zeroed before any ds atomic below

    const char* gB = (const char*)fnfr + bat_half * 8192 + lane * 16;

    bf16x8 b[2][4];    // [nt][ks] — single set, reloaded (WAR) after last MFMA use
    #pragma unroll
    for (int nt = 0; nt < 2; nt++)
        #pragma unroll
        for (int ks = 0; ks < 4; ks++)
            b[nt][ks] = *(const bf16x8*)(gB + nt * 4096 + ks * 1024);

    for (int c = 0; c < 16; c++) {
        f32x4 acc[4][2];
        #pragma unroll
        for (int mt = 0; mt < 4; mt++)
            #pragma unroll
            for (int nt = 0; nt < 2; nt++)
                acc[mt][nt] = (f32x4){0.0f, 0.0f, 0.0f, 0.0f};

        #pragma unroll
        for (int ks = 0; ks < 4; ks++)
            #pragma unroll
            for (int mt = 0; mt < 4; mt++)
                #pragma unroll
                for (int nt = 0; nt < 2; nt++)
                    acc[mt][nt] = __builtin_amdgcn_mfma_f32_16x16x32_bf16(
                        af[ks][mt], b[nt][ks], acc[mt][nt], 0, 0, 0);

        // Issue next chunk's fn loads NOW (b regs dead); L2-hit latency hides
        // under the exp epilogue below.
        if (c < 15) {
            const char* gBn = gB + (c + 1) * 16384;
            #pragma unroll
            for (int nt = 0; nt < 2; nt++)
                #pragma unroll
                for (int ks = 0; ks < 4; ks++)
                    b[nt][ks] = *(const bf16x8*)(gBn + nt * 4096 + ks * 1024);
        }

        // exp(30v-30) = exp2(fma(v, 30log2e, -30log2e)); class axis is (mt, r,
        // quad) -> per-lane sums over mt,r; then 2 shuffles fold the quads.
        float s0 = 0.0f, s1 = 0.0f;
        #pragma unroll
        for (int mt = 0; mt < 4; mt++)
            #pragma unroll
            for (int r = 0; r < 4; r++) {
                s0 += __builtin_amdgcn_exp2f(fmaf(acc[mt][0][r], S2LOG2E, -S2LOG2E));
                s1 += __builtin_amdgcn_exp2f(fmaf(acc[mt][1][r], S2LOG2E, -S2LOG2E));
            }
        s0 += __shfl_xor(s0, 16); s0 += __shfl_xor(s0, 32);
        s1 += __shfl_xor(s1, 16); s1 += __shfl_xor(s1, 32);
        if (lane < 16) {
            int base = c * 64 + bat_half * 32 + l15;
            atomicAdd(&red[base], s0);
            atomicAdd(&red[base + 16], s1);
        }
    }

    __syncthreads();
    #pragma unroll
    for (int i = 0; i < 4; i++) {
        int idx = tid + i * 256;
        atomicAdd(sumexp + idx, red[idx]);
    }
}

// loss = mean softplus(M + 30 + log(sum_all - exp(pos-30)) - pos)
__global__ void loss_k(const float* __restrict__ sumexp, const float* __restrict__ pos,
                       float* __restrict__ out) {
    __shared__ float red[256];
    int t = threadIdx.x;
    float acc = 0.0f;
    #pragma unroll
    for (int i = 0; i < 4; i++) {
        int r = t + i * 256;
        float p = pos[r];
        float sneg = fmaxf(sumexp[r] - __expf(p - 30.0f), 1e-38f);
        float lse = 30.0f + logf(sneg);
        float z = MARGIN + lse - p;
        acc += fmaxf(z, 0.0f) + log1pf(__expf(-fabsf(z)));
    }
    red[t] = acc;
    __syncthreads();
    for (int s = 128; s > 0; s >>= 1) {
        if (t < s) red[t] += red[t + s];
        __syncthreads();
    }
    if (t == 0) out[0] = red[0] * (1.0f / 1024.0f);
}

__global__ void addmean_k(const float* __restrict__ fn_f32, const int* __restrict__ label,
                          const float* __restrict__ counts, float* __restrict__ outw) {
    int b = blockIdx.x, t = threadIdx.x;  // 1024 x 128
    int c = label[b];
    float cnt = counts[c];
    atomicAdd(outw + c * D + t, fn_f32[b * D + t] / cnt);
}

extern "C" void kernel_launch(void* const* d_in, const int* in_sizes, int n_in,
                              void* d_out, int out_size, void* d_ws, size_t ws_size,
                              hipStream_t stream) {
    (void)in_sizes; (void)n_in; (void)out_size; (void)ws_size;
    const float* inp   = (const float*)d_in[0];
    const int*   label = (const int*)d_in[1];
    const float* wt    = (const float*)d_in[2];
    float* out = (float*)d_out;

    char* w = (char*)d_ws;
    float*          fn_f32 = (float*)(w);                     // 524288 B
    unsigned short* fn_fr  = (unsigned short*)(w + 524288);   // 262144 B
    unsigned short* wn_fr  = (unsigned short*)(w + 786432);   // 25624576 B
    float*          sumexp = (float*)(w + 26411008);          // 4096 B
    float*          counts = (float*)(w + 26415104);          // 400000 B
    float*          pos    = (float*)(w + 26815104);          // 4096 B

    // zero sumexp + counts (contiguous)
    hipMemsetAsync(w + 26411008, 0, 404096, stream);

    prep_fn<<<BS / 4, 256, 0, stream>>>(inp, label, wt, fn_f32, fn_fr, counts, pos);
    prep_wn<<<NCP / 4, 256, 0, stream>>>(wt, counts, wn_fr, out + 1);
    main_gemm<<<NTILES, 256, 0, stream>>>(fn_fr, wn_fr, sumexp);
    addmean_k<<<BS, D, 0, stream>>>(fn_f32, label, counts, out + 1);
    loss_k<<<1, 256, 0, stream>>>(sumexp, pos, out);
}